// Round 1
// 242.239 us; speedup vs baseline: 1.0118x; 1.0118x over previous
//
#include <hip/hip_runtime.h>
#include <math.h>

#define FEAT 64
#define NKERN 3

typedef __attribute__((ext_vector_type(8))) short short8;
typedef __attribute__((ext_vector_type(4))) float float4v;

__device__ __forceinline__ unsigned short f2bf(float f) {
    unsigned int u = __float_as_uint(f);
    u = (u + 0x7fffu + ((u >> 16) & 1u)) >> 16;   // round-to-nearest-even
    return (unsigned short)u;
}
__device__ __forceinline__ float bf2f(unsigned short b) {
    return __uint_as_float(((unsigned int)b) << 16);
}

// fast tanh: 1 - 2/(e^{2x}+1), exact at +-inf, bf16-level accurate
__device__ __forceinline__ float fast_tanh(float x) {
    float e = __expf(2.f * x);
    return fmaf(-2.f, __builtin_amdgcn_rcpf(e + 1.f), 1.f);
}

// feat (fp32) -> bf16, 4 elems/thread
__global__ __launch_bounds__(256) void cast_kernel(
    const float* __restrict__ x, unsigned short* __restrict__ y, int n4)
{
    int i = blockIdx.x * 256 + threadIdx.x;
    if (i >= n4) return;
    float4 v = ((const float4*)x)[i];
    ushort4 o;
    o.x = f2bf(v.x); o.y = f2bf(v.y); o.z = f2bf(v.z); o.w = f2bf(v.w);
    ((ushort4*)y)[i] = o;
}

// fcW[l][j][k*64+f] -> Bt hi/lo in MFMA B-fragment tiled order:
// frag element (f, jp): ft=f>>4, n=f&15, ks=jp>>5, q=(jp>>3)&3, e=jp&7
// dst = l*12288 + (((ft*6+ks)*4+q)*16 + n)*8 + e
__global__ __launch_bounds__(256) void wprep_kernel(
    const float* __restrict__ fcW,
    unsigned short* __restrict__ Bth, unsigned short* __restrict__ Btl,
    int total)  // L*64*192
{
    int idx = blockIdx.x * 256 + threadIdx.x;
    if (idx >= total) return;
    int l   = idx / (FEAT * 192);
    int rem = idx - l * (FEAT * 192);
    int f   = rem / 192;
    int jp  = rem - f * 192;
    int k = jp >> 6, j = jp & 63;
    float v = fcW[(size_t)l * 12288 + j * 192 + k * 64 + f];
    unsigned short hi = f2bf(v);
    int dst = l * 12288 +
              ((((f >> 4) * 6 + (jp >> 5)) * 4 + ((jp >> 3) & 3)) * 16 + (f & 15)) * 8 +
              (jp & 7);
    Bth[dst] = hi;
    Btl[dst] = f2bf(v - bf2f(hi));
}

// Per-edge Gaussian kernel weights for ALL layers in one pass (pseudo read once).
__global__ __launch_bounds__(256) void wk3_kernel(
    const float* __restrict__ pseudo,  // [E, 2]
    const float* __restrict__ projW,   // [L, 2, 2]
    const float* __restrict__ projB,   // [L, 2]
    const float* __restrict__ mu,      // [L, 3, 2]
    const float* __restrict__ isg,     // [L, 3, 2]
    float* __restrict__ wbuf3,         // [L, E, 3]
    int n_edges, int n_layers)
{
    int e = blockIdx.x * 256 + threadIdx.x;
    if (e >= n_edges) return;
    float2 p = ((const float2*)pseudo)[e];
    for (int l = 0; l < n_layers; ++l) {
        const float* pw = projW + l * 4;
        const float* pb = projB + l * 2;
        const float* m_ = mu  + l * 6;
        const float* s_ = isg + l * 6;
        float u0 = fast_tanh(fmaf(p.x, pw[0], fmaf(p.y, pw[2], pb[0])));
        float u1 = fast_tanh(fmaf(p.x, pw[1], fmaf(p.y, pw[3], pb[1])));
        float d0, d1, s0, s1;
        d0 = u0 - m_[0]; d1 = u1 - m_[1]; s0 = s_[0]; s1 = s_[1];
        float w0 = __expf(-0.5f * (d0*d0*s0*s0 + d1*d1*s1*s1));
        d0 = u0 - m_[2]; d1 = u1 - m_[3]; s0 = s_[2]; s1 = s_[3];
        float w1 = __expf(-0.5f * (d0*d0*s0*s0 + d1*d1*s1*s1));
        d0 = u0 - m_[4]; d1 = u1 - m_[5]; s0 = s_[4]; s1 = s_[5];
        float w2 = __expf(-0.5f * (d0*d0*s0*s0 + d1*d1*s1*s1));
        float* wp = wbuf3 + ((size_t)l * n_edges + e) * 3;
        wp[0] = w0; wp[1] = w1; wp[2] = w2;
    }
}

// One fused layer, restructured: block = 4 waves = 256 threads, tile = 16 nodes.
// Phase 1: wave w gathers/accumulates nodes m = 4w..4w+3 (serial per wave),
//   writing bf16 A-fragments into a bank-swizzled LDS tile.
// Phase 2: ALL 4 waves do MFMA (wave = f-tile) -> no idle waves, and 8
//   small blocks/CU decorrelate barrier convoys.
// Atile strides: e-stride 1, m-stride 8, q-stride 136 (272 B), ks-stride 544.
//   Store banks: 16*ksl + 4q + 4m + e/2 mod 32 -> all 32 banks, conflict-free.
__global__ __launch_bounds__(256, 8) void layer_kernel(
    const unsigned short* __restrict__ h,    // [N, 64] bf16
    const int*   __restrict__ rowptr,        // [N+1]
    const int*   __restrict__ colind,        // [E]
    const float* __restrict__ wbuf,          // [E, 3] this layer
    const unsigned short* __restrict__ Bth,  // frag-tiled, this layer
    const unsigned short* __restrict__ Btl,
    float* __restrict__ out,                 // [N,64] fp32 (last layer)
    unsigned short* __restrict__ hnext,      // [N,64] bf16 (mid layers)
    int n_nodes, int last_layer)
{
    __shared__ __align__(16) unsigned short Atile[3264];  // 6 ks * 544, 6528 B
    int tid  = threadIdx.x;
    int w    = tid >> 6;          // wave 0..3
    int lane = tid & 63;
    int t0   = blockIdx.x * 16;

    // A-frag store address for this lane (feature j = lane):
    // ks2 = lane>>5, q = (lane>>3)&3, e = lane&7
    int stbase = (lane >> 5) * 544 + ((lane >> 3) & 3) * 136 + (lane & 7);

    for (int s = 0; s < 4; ++s) {
        int m = w * 4 + s;
        int node = t0 + m;
        float a0 = 0.f, a1 = 0.f, a2 = 0.f;
        if (node < n_nodes) {
            int nu  = __builtin_amdgcn_readfirstlane(node);
            int r0  = rowptr[nu];
            int deg = rowptr[nu + 1] - r0;   // fixed 32 in this problem
            if (deg == 32) {
                unsigned short v[32];
                #pragma unroll
                for (int i = 0; i < 32; ++i) {
                    int cc = colind[r0 + i];             // uniform -> s_load
                    v[i] = h[(size_t)cc * FEAT + lane];  // coalesced 128B gather
                }
                #pragma unroll
                for (int i = 0; i < 32; ++i) {
                    const float* wp = wbuf + (size_t)(r0 + i) * 3;  // uniform s_load
                    float vf = bf2f(v[i]);
                    a0 = fmaf(wp[0], vf, a0);
                    a1 = fmaf(wp[1], vf, a1);
                    a2 = fmaf(wp[2], vf, a2);
                }
            } else {
                for (int i = 0; i < deg; ++i) {
                    int cc = colind[r0 + i];
                    float vf = bf2f(h[(size_t)cc * FEAT + lane]);
                    const float* wp = wbuf + (size_t)(r0 + i) * 3;
                    a0 = fmaf(wp[0], vf, a0);
                    a1 = fmaf(wp[1], vf, a1);
                    a2 = fmaf(wp[2], vf, a2);
                }
            }
        }
        int sb = stbase + m * 8;
        Atile[sb]        = f2bf(a0);   // k=0 -> ks 0,1
        Atile[sb + 1088] = f2bf(a1);   // k=1 -> ks 2,3 (+2*544)
        Atile[sb + 2176] = f2bf(a2);   // k=2 -> ks 4,5
    }
    __syncthreads();

    // Phase 2: wave w = f-tile ft; B hi/lo frags from pre-tiled, L2-resident Bt.
    int q  = lane >> 4;
    int nn = lane & 15;
    const unsigned short* bt0 = Bth + (((w * 6) * 4 + q) * 16 + nn) * 8;
    const unsigned short* bt1 = Btl + (((w * 6) * 4 + q) * 16 + nn) * 8;
    float4v acc = (float4v){0.f, 0.f, 0.f, 0.f};
    #pragma unroll
    for (int ks = 0; ks < 6; ++ks) {
        short8 ah = *(const short8*)&Atile[ks * 544 + q * 136 + nn * 8];
        short8 bh = *(const short8*)(bt0 + ks * 512);
        short8 bl = *(const short8*)(bt1 + ks * 512);
        acc = __builtin_amdgcn_mfma_f32_16x16x32_bf16(ah, bh, acc, 0, 0, 0);
        acc = __builtin_amdgcn_mfma_f32_16x16x32_bf16(ah, bl, acc, 0, 0, 0);
    }
    // D: col f = w*16+nn, row = t0 + q*4 + r
    #pragma unroll
    for (int r = 0; r < 4; ++r) {
        int row = t0 + q * 4 + r;
        if (row < n_nodes) {
            if (last_layer)
                out[(size_t)row * 64 + w * 16 + nn] = acc[r];
            else
                hnext[(size_t)row * 64 + w * 16 + nn] = f2bf(acc[r]);
        }
    }
}

extern "C" void kernel_launch(void* const* d_in, const int* in_sizes, int n_in,
                              void* d_out, int out_size, void* d_ws, size_t ws_size,
                              hipStream_t stream)
{
    const float* feat   = (const float*)d_in[0];   // [N, 64]
    const float* pseudo = (const float*)d_in[1];   // [E, 2]
    const int*   rowptr = (const int*)d_in[2];     // [N+1]
    const int*   colind = (const int*)d_in[3];     // [E]
    const float* projW  = (const float*)d_in[4];   // [L, 2, 2]
    const float* projB  = (const float*)d_in[5];   // [L, 2]
    const float* fcW    = (const float*)d_in[6];   // [L, 64, 192]
    const float* mu     = (const float*)d_in[7];   // [L, 3, 2]
    const float* isg    = (const float*)d_in[8];   // [L, 3, 2]
    float* out = (float*)d_out;

    int n  = in_sizes[0] / FEAT;                        // 50000
    int e  = in_sizes[3];                               // 1.6M
    int n_layers = in_sizes[6] / (FEAT * NKERN * FEAT); // 3

    unsigned short* hbA = (unsigned short*)d_ws;                  // n*64
    unsigned short* hbB = hbA + (size_t)n * FEAT;                 // n*64
    unsigned short* Bth = hbB + (size_t)n * FEAT;                 // L*12288
    unsigned short* Btl = Bth + (size_t)n_layers * 12288;         // L*12288
    float* wbuf3 = (float*)(Btl + (size_t)n_layers * 12288);      // L*e*3

    dim3 blk(256);
    dim3 castGrid((n * FEAT / 4 + 255) / 256);
    dim3 wpGrid((n_layers * FEAT * 192 + 255) / 256);
    dim3 wkGrid((e + 255) / 256);
    dim3 layerGrid((n + 15) / 16);
    dim3 layerBlk(256);

    cast_kernel<<<castGrid, blk, 0, stream>>>(feat, hbA, n * FEAT / 4);
    wprep_kernel<<<wpGrid, blk, 0, stream>>>(fcW, Bth, Btl, n_layers * FEAT * 192);
    wk3_kernel<<<wkGrid, blk, 0, stream>>>(
        pseudo, projW, projB, mu, isg, wbuf3, e, n_layers);

    const unsigned short* hin = hbA;
    for (int l = 0; l < n_layers; ++l) {
        int last = (l == n_layers - 1);
        unsigned short* hb_out = (l == 0) ? hbB : hbA;
        layer_kernel<<<layerGrid, layerBlk, 0, stream>>>(
            hin, rowptr, colind, wbuf3 + (size_t)l * e * 3,
            Bth + (size_t)l * 12288, Btl + (size_t)l * 12288,
            out, hb_out, n, last);
        hin = hb_out;
    }
}

// Round 2
// 212.352 us; speedup vs baseline: 1.1542x; 1.1407x over previous
//
#include <hip/hip_runtime.h>
#include <math.h>

#define FEAT 64
#define NKERN 3

typedef __attribute__((ext_vector_type(8))) short short8;
typedef __attribute__((ext_vector_type(4))) float float4v;

__device__ __forceinline__ unsigned short f2bf(float f) {
    unsigned int u = __float_as_uint(f);
    u = (u + 0x7fffu + ((u >> 16) & 1u)) >> 16;   // round-to-nearest-even
    return (unsigned short)u;
}
__device__ __forceinline__ float bf2f(unsigned short b) {
    return __uint_as_float(((unsigned int)b) << 16);
}
// fast tanh: 1 - 2/(e^{2x}+1), exact at +-inf, bf16-level accurate
__device__ __forceinline__ float fast_tanh(float x) {
    float e = __expf(2.f * x);
    return fmaf(-2.f, __builtin_amdgcn_rcpf(e + 1.f), 1.f);
}
// broadcast lane i's float to all lanes (i must be wave-uniform / literal)
__device__ __forceinline__ float lanebcast(float v, int i) {
    return __uint_as_float((unsigned)__builtin_amdgcn_readlane((int)__float_as_uint(v), i));
}

// feat (fp32) -> bf16, 4 elems/thread
__global__ __launch_bounds__(256) void cast_kernel(
    const float* __restrict__ x, unsigned short* __restrict__ y, int n4)
{
    int i = blockIdx.x * 256 + threadIdx.x;
    if (i >= n4) return;
    float4 v = ((const float4*)x)[i];
    ushort4 o;
    o.x = f2bf(v.x); o.y = f2bf(v.y); o.z = f2bf(v.z); o.w = f2bf(v.w);
    ((ushort4*)y)[i] = o;
}

// fcW[l][j][k*64+f] -> Bt hi/lo in MFMA B-fragment tiled order:
// frag element (f, jp): ft=f>>4, n=f&15, ks=jp>>5, q=(jp>>3)&3, e=jp&7
// dst = l*12288 + (((ft*6+ks)*4+q)*16 + n)*8 + e
__global__ __launch_bounds__(256) void wprep_kernel(
    const float* __restrict__ fcW,
    unsigned short* __restrict__ Bth, unsigned short* __restrict__ Btl,
    int total)  // L*64*192
{
    int idx = blockIdx.x * 256 + threadIdx.x;
    if (idx >= total) return;
    int l   = idx / (FEAT * 192);
    int rem = idx - l * (FEAT * 192);
    int f   = rem / 192;
    int jp  = rem - f * 192;
    int k = jp >> 6, j = jp & 63;
    float v = fcW[(size_t)l * 12288 + j * 192 + k * 64 + f];
    unsigned short hi = f2bf(v);
    int dst = l * 12288 +
              ((((f >> 4) * 6 + (jp >> 5)) * 4 + ((jp >> 3) & 3)) * 16 + (f & 15)) * 8 +
              (jp & 7);
    Bth[dst] = hi;
    Btl[dst] = f2bf(v - bf2f(hi));
}

// One fused layer: block = 4 waves = 256 threads, tile = 16 nodes.
// Phase 1: wave w gathers/accumulates nodes m = 4w..4w+3.
//   ALL per-edge data (colind, pseudo) comes in via coalesced VECTOR loads
//   (lane = edge), then wave-uniform values are produced with v_readlane —
//   no streaming scalar loads (the SQC-miss serial chain was the bottleneck).
//   Gaussian kernel weights are computed in-kernel from pseudo (wk3 fused away).
// Phase 2: ALL 4 waves do MFMA (wave = f-tile).
// Atile strides: e-stride 1, m-stride 8, q-stride 136 (272 B), ks-stride 544:
//   conflict-free stores and reads.
__global__ __launch_bounds__(256, 8) void layer_kernel(
    const unsigned short* __restrict__ h,    // [N, 64] bf16
    const int*   __restrict__ rowptr,        // [N+1]
    const int*   __restrict__ colind,        // [E]
    const float* __restrict__ pseudo,        // [E, 2]
    const float* __restrict__ projW,         // [L, 2, 2]
    const float* __restrict__ projB,         // [L, 2]
    const float* __restrict__ mu,            // [L, 3, 2]
    const float* __restrict__ isg,           // [L, 3, 2]
    int layer,
    const unsigned short* __restrict__ Bth,  // frag-tiled, this layer
    const unsigned short* __restrict__ Btl,
    float* __restrict__ out,                 // [N,64] fp32 (last layer)
    unsigned short* __restrict__ hnext,      // [N,64] bf16 (mid layers)
    int n_nodes, int last_layer)
{
    __shared__ __align__(16) unsigned short Atile[3264];  // 6 ks * 544, 6528 B
    int tid  = threadIdx.x;
    int w    = tid >> 6;          // wave 0..3
    int lane = tid & 63;
    int t0   = blockIdx.x * 16;

    // per-layer constants (uniform s_loads, once)
    const float* pw = projW + layer * 4;
    const float* pb = projB + layer * 2;
    const float* mm = mu  + layer * 6;
    const float* ss = isg + layer * 6;
    float pw0 = pw[0], pw1 = pw[1], pw2 = pw[2], pw3 = pw[3];
    float pb0 = pb[0], pb1 = pb[1];
    float m0 = mm[0], m1 = mm[1], m2 = mm[2], m3 = mm[3], m4 = mm[4], m5 = mm[5];
    float c0 = -0.5f * ss[0] * ss[0], c1 = -0.5f * ss[1] * ss[1];
    float c2 = -0.5f * ss[2] * ss[2], c3 = -0.5f * ss[3] * ss[3];
    float c4 = -0.5f * ss[4] * ss[4], c5 = -0.5f * ss[5] * ss[5];

    // A-frag store address for this lane (feature j = lane):
    int stbase = (lane >> 5) * 544 + ((lane >> 3) & 3) * 136 + (lane & 7);

    for (int s = 0; s < 4; ++s) {
        int m = w * 4 + s;
        int node = t0 + m;
        float a0 = 0.f, a1 = 0.f, a2 = 0.f;
        if (node < n_nodes) {
            int nu  = __builtin_amdgcn_readfirstlane(node);
            int r0  = rowptr[nu];
            int deg = rowptr[nu + 1] - r0;   // fixed 32 in this problem
            if (deg == 32) {
                int li = lane & 31;
                // coalesced vector loads: lane = edge
                int    ccl = colind[r0 + li];
                float2 ps  = ((const float2*)pseudo)[r0 + li];
                // per-lane (per-edge) Gaussian weights
                float u0 = fast_tanh(fmaf(ps.x, pw0, fmaf(ps.y, pw2, pb0)));
                float u1 = fast_tanh(fmaf(ps.x, pw1, fmaf(ps.y, pw3, pb1)));
                float d0 = u0 - m0, d1 = u1 - m1;
                float w0v = __expf(fmaf(d0 * d0, c0, d1 * d1 * c1));
                d0 = u0 - m2; d1 = u1 - m3;
                float w1v = __expf(fmaf(d0 * d0, c2, d1 * d1 * c3));
                d0 = u0 - m4; d1 = u1 - m5;
                float w2v = __expf(fmaf(d0 * d0, c4, d1 * d1 * c5));

                unsigned short v[32];
                #pragma unroll
                for (int i = 0; i < 32; ++i) {
                    int cc = __builtin_amdgcn_readlane(ccl, i);   // uniform row
                    v[i] = h[(size_t)cc * FEAT + lane];           // coalesced 128B gather
                }
                #pragma unroll
                for (int i = 0; i < 32; ++i) {
                    float vf = bf2f(v[i]);
                    a0 = fmaf(lanebcast(w0v, i), vf, a0);
                    a1 = fmaf(lanebcast(w1v, i), vf, a1);
                    a2 = fmaf(lanebcast(w2v, i), vf, a2);
                }
            } else {
                for (int i = 0; i < deg; ++i) {
                    int cc = colind[r0 + i];
                    float px = pseudo[(size_t)(r0 + i) * 2];
                    float py = pseudo[(size_t)(r0 + i) * 2 + 1];
                    float u0 = fast_tanh(fmaf(px, pw0, fmaf(py, pw2, pb0)));
                    float u1 = fast_tanh(fmaf(px, pw1, fmaf(py, pw3, pb1)));
                    float d0 = u0 - m0, d1 = u1 - m1;
                    float w0e = __expf(fmaf(d0 * d0, c0, d1 * d1 * c1));
                    d0 = u0 - m2; d1 = u1 - m3;
                    float w1e = __expf(fmaf(d0 * d0, c2, d1 * d1 * c3));
                    d0 = u0 - m4; d1 = u1 - m5;
                    float w2e = __expf(fmaf(d0 * d0, c4, d1 * d1 * c5));
                    float vf = bf2f(h[(size_t)cc * FEAT + lane]);
                    a0 = fmaf(w0e, vf, a0);
                    a1 = fmaf(w1e, vf, a1);
                    a2 = fmaf(w2e, vf, a2);
                }
            }
        }
        int sb = stbase + m * 8;
        Atile[sb]        = f2bf(a0);   // k=0 -> ks 0,1
        Atile[sb + 1088] = f2bf(a1);   // k=1 -> ks 2,3 (+2*544)
        Atile[sb + 2176] = f2bf(a2);   // k=2 -> ks 4,5
    }
    __syncthreads();

    // Phase 2: wave w = f-tile ft; B hi/lo frags from pre-tiled, L2-resident Bt.
    int q  = lane >> 4;
    int nn = lane & 15;
    const unsigned short* bt0 = Bth + (((w * 6) * 4 + q) * 16 + nn) * 8;
    const unsigned short* bt1 = Btl + (((w * 6) * 4 + q) * 16 + nn) * 8;
    float4v acc = (float4v){0.f, 0.f, 0.f, 0.f};
    #pragma unroll
    for (int ks = 0; ks < 6; ++ks) {
        short8 ah = *(const short8*)&Atile[ks * 544 + q * 136 + nn * 8];
        short8 bh = *(const short8*)(bt0 + ks * 512);
        short8 bl = *(const short8*)(bt1 + ks * 512);
        acc = __builtin_amdgcn_mfma_f32_16x16x32_bf16(ah, bh, acc, 0, 0, 0);
        acc = __builtin_amdgcn_mfma_f32_16x16x32_bf16(ah, bl, acc, 0, 0, 0);
    }
    // D: col f = w*16+nn, row = t0 + q*4 + r
    #pragma unroll
    for (int r = 0; r < 4; ++r) {
        int row = t0 + q * 4 + r;
        if (row < n_nodes) {
            if (last_layer)
                out[(size_t)row * 64 + w * 16 + nn] = acc[r];
            else
                hnext[(size_t)row * 64 + w * 16 + nn] = f2bf(acc[r]);
        }
    }
}

extern "C" void kernel_launch(void* const* d_in, const int* in_sizes, int n_in,
                              void* d_out, int out_size, void* d_ws, size_t ws_size,
                              hipStream_t stream)
{
    const float* feat   = (const float*)d_in[0];   // [N, 64]
    const float* pseudo = (const float*)d_in[1];   // [E, 2]
    const int*   rowptr = (const int*)d_in[2];     // [N+1]
    const int*   colind = (const int*)d_in[3];     // [E]
    const float* projW  = (const float*)d_in[4];   // [L, 2, 2]
    const float* projB  = (const float*)d_in[5];   // [L, 2]
    const float* fcW    = (const float*)d_in[6];   // [L, 64, 192]
    const float* mu     = (const float*)d_in[7];   // [L, 3, 2]
    const float* isg    = (const float*)d_in[8];   // [L, 3, 2]
    float* out = (float*)d_out;

    int n  = in_sizes[0] / FEAT;                        // 50000
    int e  = in_sizes[3];                               // 1.6M (unused)
    (void)e;
    int n_layers = in_sizes[6] / (FEAT * NKERN * FEAT); // 3

    unsigned short* hbA = (unsigned short*)d_ws;                  // n*64
    unsigned short* hbB = hbA + (size_t)n * FEAT;                 // n*64
    unsigned short* Bth = hbB + (size_t)n * FEAT;                 // L*12288
    unsigned short* Btl = Bth + (size_t)n_layers * 12288;         // L*12288

    dim3 blk(256);
    dim3 castGrid((n * FEAT / 4 + 255) / 256);
    dim3 wpGrid((n_layers * FEAT * 192 + 255) / 256);
    dim3 layerGrid((n + 15) / 16);
    dim3 layerBlk(256);

    cast_kernel<<<castGrid, blk, 0, stream>>>(feat, hbA, n * FEAT / 4);
    wprep_kernel<<<wpGrid, blk, 0, stream>>>(fcW, Bth, Btl, n_layers * FEAT * 192);

    const unsigned short* hin = hbA;
    for (int l = 0; l < n_layers; ++l) {
        int last = (l == n_layers - 1);
        unsigned short* hb_out = (l == 0) ? hbB : hbA;
        layer_kernel<<<layerGrid, layerBlk, 0, stream>>>(
            hin, rowptr, colind, pseudo, projW, projB, mu, isg, l,
            Bth + (size_t)l * 12288, Btl + (size_t)l * 12288,
            out, hb_out, n, last);
        hin = hb_out;
    }
}

// Round 3
// 167.777 us; speedup vs baseline: 1.4608x; 1.2657x over previous
//
#include <hip/hip_runtime.h>
#include <math.h>

#define FEAT 64
#define NKERN 3

typedef __attribute__((ext_vector_type(8))) short short8;
typedef __attribute__((ext_vector_type(4))) float float4v;
typedef __attribute__((ext_vector_type(2))) float float2v;

__device__ __forceinline__ unsigned short f2bf(float f) {
    unsigned int u = __float_as_uint(f);
    u = (u + 0x7fffu + ((u >> 16) & 1u)) >> 16;   // round-to-nearest-even
    return (unsigned short)u;
}
__device__ __forceinline__ float bf2f(unsigned short b) {
    return __uint_as_float(((unsigned int)b) << 16);
}
// fast tanh: 1 - 2/(e^{2x}+1), exact at +-inf, bf16-level accurate
__device__ __forceinline__ float fast_tanh(float x) {
    float e = __expf(2.f * x);
    return fmaf(-2.f, __builtin_amdgcn_rcpf(e + 1.f), 1.f);
}

// Combined prep: feat fp32->bf16 cast (first nCastBlocks) + fcW frag-tiling.
__global__ __launch_bounds__(256) void prep_kernel(
    const float* __restrict__ x, unsigned short* __restrict__ y, int n4,
    const float* __restrict__ fcW,
    unsigned short* __restrict__ Bth, unsigned short* __restrict__ Btl,
    int totalW, int nCastBlocks)
{
    int b = blockIdx.x;
    if (b < nCastBlocks) {
        int i = b * 256 + threadIdx.x;
        if (i >= n4) return;
        float4 v = ((const float4*)x)[i];
        ushort4 o;
        o.x = f2bf(v.x); o.y = f2bf(v.y); o.z = f2bf(v.z); o.w = f2bf(v.w);
        ((ushort4*)y)[i] = o;
    } else {
        int idx = (b - nCastBlocks) * 256 + threadIdx.x;
        if (idx >= totalW) return;
        int l   = idx / (FEAT * 192);
        int rem = idx - l * (FEAT * 192);
        int f   = rem / 192;
        int jp  = rem - f * 192;
        int k = jp >> 6, j = jp & 63;
        float v = fcW[(size_t)l * 12288 + j * 192 + k * 64 + f];
        unsigned short hi = f2bf(v);
        int dst = l * 12288 +
                  ((((f >> 4) * 6 + (jp >> 5)) * 4 + ((jp >> 3) & 3)) * 16 + (f & 15)) * 8 +
                  (jp & 7);
        Bth[dst] = hi;
        Btl[dst] = f2bf(v - bf2f(hi));
    }
}

// One fused layer: block = 4 waves = 256 threads, tile = 16 nodes.
// Phase 1: each wave handles 4 nodes as 2 node-PAIRS. Lane split:
//   half = lane>>5 (node of pair), p = lane&31 (feature pair 2p,2p+1).
//   Step A (lane = (node,edge)): coalesced colind/pseudo loads, per-edge
//     Gaussian weights, one 16B LDS record [cc<<7, w0, w1, w2] per edge.
//   Step B (lane = (node,featpair)): per edge i: ds_read_b128 record
//     (2-address broadcast, conflict-free), dword gather (4B/lane = 256B/instr),
//     2 unpack ops, 3 packed-f32 FMAs. No readlanes, no scalar-load streams.
//   Epilogue: v_cvt_pk_bf16_f32 + dword stores into MFMA A-frag LDS layout.
// Phase 2: ALL 4 waves do MFMA (wave = f-tile), unchanged from prev round.
__global__ __launch_bounds__(256, 4) void layer_kernel(
    const unsigned short* __restrict__ h,    // [N, 64] bf16
    const int*   __restrict__ rowptr,        // [N+1]
    const int*   __restrict__ colind,        // [E]
    const float* __restrict__ pseudo,        // [E, 2]
    const float* __restrict__ projW,         // [L, 2, 2]
    const float* __restrict__ projB,         // [L, 2]
    const float* __restrict__ mu,            // [L, 3, 2]
    const float* __restrict__ isg,           // [L, 3, 2]
    int layer,
    const unsigned short* __restrict__ Bth,  // frag-tiled, this layer
    const unsigned short* __restrict__ Btl,
    float* __restrict__ out,                 // [N,64] fp32 (last layer)
    unsigned short* __restrict__ hnext,      // [N,64] bf16 (mid layers)
    int n_nodes, int last_layer)
{
    __shared__ __align__(16) unsigned short Atile[3264];      // 6 ks * 544 shorts
    __shared__ __align__(16) unsigned int   WldsU[4][2][132]; // per wave, per node-slot
    int tid  = threadIdx.x;
    int wv   = tid >> 6;
    int lane = tid & 63;
    int t0   = blockIdx.x * 16;

    // per-layer constants (uniform s_loads, once)
    const float* pw = projW + layer * 4;
    const float* pb = projB + layer * 2;
    const float* mm = mu  + layer * 6;
    const float* ss = isg + layer * 6;
    float pw0 = pw[0], pw1 = pw[1], pw2 = pw[2], pw3 = pw[3];
    float pb0 = pb[0], pb1 = pb[1];
    float m0 = mm[0], m1 = mm[1], m2 = mm[2], m3 = mm[3], m4 = mm[4], m5 = mm[5];
    float c0 = -0.5f * ss[0] * ss[0], c1 = -0.5f * ss[1] * ss[1];
    float c2 = -0.5f * ss[2] * ss[2], c3 = -0.5f * ss[3] * ss[3];
    float c4 = -0.5f * ss[4] * ss[4], c5 = -0.5f * ss[5] * ss[5];

    int half = lane >> 5;
    int p    = lane & 31;
    unsigned int featoff = (unsigned int)(p * 4);   // byte off of feat pair in bf16 row
    const char* hb = (const char*)h;

    for (int s2 = 0; s2 < 2; ++s2) {
        int nA    = t0 + wv * 4 + s2 * 2;
        int nodeh = nA + half;
        int ncl   = nodeh < n_nodes - 1 ? nodeh : (n_nodes - 1);
        int rp    = rowptr[ncl];
        int deg   = rowptr[ncl + 1] - rp;
        bool fast = __all((deg == 32) && (nodeh < n_nodes));

        if (fast) {
            // ---- Step A: lane = (node=half, edge=p) ----
            int ei = rp + p;
            int cc = colind[ei];                       // coalesced dword
            float2 ps = ((const float2*)pseudo)[ei];   // coalesced 8B
            float u0 = fast_tanh(fmaf(ps.x, pw0, fmaf(ps.y, pw2, pb0)));
            float u1 = fast_tanh(fmaf(ps.x, pw1, fmaf(ps.y, pw3, pb1)));
            float d0 = u0 - m0, d1 = u1 - m1;
            float w0v = __expf(fmaf(d0 * d0, c0, d1 * d1 * c1));
            d0 = u0 - m2; d1 = u1 - m3;
            float w1v = __expf(fmaf(d0 * d0, c2, d1 * d1 * c3));
            d0 = u0 - m4; d1 = u1 - m5;
            float w2v = __expf(fmaf(d0 * d0, c4, d1 * d1 * c5));
            uint4 recw;
            recw.x = ((unsigned int)cc) << 7;          // byte offset of row
            recw.y = __float_as_uint(w0v);
            recw.z = __float_as_uint(w1v);
            recw.w = __float_as_uint(w2v);
            *(uint4*)&WldsU[wv][half][p * 4] = recw;   // ds_write_b128, conflict-free

            // ---- Step B: lane = (node=half, featpair=p) ----
            float2v a0 = {0.f, 0.f}, a1 = {0.f, 0.f}, a2 = {0.f, 0.f};
            const unsigned int* Wrec = &WldsU[wv][half][0];
            #pragma unroll
            for (int i = 0; i < 32; ++i) {
                uint4 rec = *(const uint4*)(Wrec + i * 4);  // 2-addr broadcast b128
                unsigned int hv = *(const unsigned int*)(hb + (rec.x + featoff));
                float2v vf;
                vf.x = __uint_as_float(hv << 16);
                vf.y = __uint_as_float(hv & 0xffff0000u);
                float w0 = __uint_as_float(rec.y);
                float w1 = __uint_as_float(rec.z);
                float w2 = __uint_as_float(rec.w);
#if __has_builtin(__builtin_elementwise_fma)
                float2v w0s = {w0, w0}, w1s = {w1, w1}, w2s = {w2, w2};
                a0 = __builtin_elementwise_fma(vf, w0s, a0);
                a1 = __builtin_elementwise_fma(vf, w1s, a1);
                a2 = __builtin_elementwise_fma(vf, w2s, a2);
#else
                a0.x = fmaf(vf.x, w0, a0.x); a0.y = fmaf(vf.y, w0, a0.y);
                a1.x = fmaf(vf.x, w1, a1.x); a1.y = fmaf(vf.y, w1, a1.y);
                a2.x = fmaf(vf.x, w2, a2.x); a2.y = fmaf(vf.y, w2, a2.y);
#endif
            }
            // ---- epilogue: pack 2 feats -> dword, A-frag layout ----
            int m  = wv * 4 + s2 * 2 + half;
            int j0 = p * 2;   // even, j0&7 <= 6 -> pair stays in one 8-short group
            int sa = (j0 >> 5) * 544 + ((j0 >> 3) & 3) * 136 + m * 8 + (j0 & 7);
            unsigned int pk0, pk1, pk2;
            asm("v_cvt_pk_bf16_f32 %0, %1, %2" : "=v"(pk0) : "v"(a0.x), "v"(a0.y));
            asm("v_cvt_pk_bf16_f32 %0, %1, %2" : "=v"(pk1) : "v"(a1.x), "v"(a1.y));
            asm("v_cvt_pk_bf16_f32 %0, %1, %2" : "=v"(pk2) : "v"(a2.x), "v"(a2.y));
            *(unsigned int*)&Atile[sa]        = pk0;
            *(unsigned int*)&Atile[sa + 1088] = pk1;
            *(unsigned int*)&Atile[sa + 2176] = pk2;
        } else {
            // slow path: per node serial, lane = feature (rare/tail only)
            for (int t = 0; t < 2; ++t) {
                int node = nA + t;
                float a0 = 0.f, a1 = 0.f, a2 = 0.f;
                if (node < n_nodes) {
                    int nu = __builtin_amdgcn_readfirstlane(node);
                    int r0 = rowptr[nu];
                    int dg = rowptr[nu + 1] - r0;
                    for (int i = 0; i < dg; ++i) {
                        int cc = colind[r0 + i];
                        float px = pseudo[(size_t)(r0 + i) * 2];
                        float py = pseudo[(size_t)(r0 + i) * 2 + 1];
                        float u0 = fast_tanh(fmaf(px, pw0, fmaf(py, pw2, pb0)));
                        float u1 = fast_tanh(fmaf(px, pw1, fmaf(py, pw3, pb1)));
                        float d0 = u0 - m0, d1 = u1 - m1;
                        float w0e = __expf(fmaf(d0 * d0, c0, d1 * d1 * c1));
                        d0 = u0 - m2; d1 = u1 - m3;
                        float w1e = __expf(fmaf(d0 * d0, c2, d1 * d1 * c3));
                        d0 = u0 - m4; d1 = u1 - m5;
                        float w2e = __expf(fmaf(d0 * d0, c4, d1 * d1 * c5));
                        float vf = bf2f(h[(size_t)cc * FEAT + lane]);
                        a0 = fmaf(w0e, vf, a0);
                        a1 = fmaf(w1e, vf, a1);
                        a2 = fmaf(w2e, vf, a2);
                    }
                }
                int m  = wv * 4 + s2 * 2 + t;
                int sb = (lane >> 5) * 544 + ((lane >> 3) & 3) * 136 + m * 8 + (lane & 7);
                Atile[sb]        = f2bf(a0);
                Atile[sb + 1088] = f2bf(a1);
                Atile[sb + 2176] = f2bf(a2);
            }
        }
    }
    __syncthreads();

    // Phase 2: wave wv = f-tile; B hi/lo frags from pre-tiled, L2-resident Bt.
    int q  = lane >> 4;
    int nn = lane & 15;
    const unsigned short* bt0 = Bth + (((wv * 6) * 4 + q) * 16 + nn) * 8;
    const unsigned short* bt1 = Btl + (((wv * 6) * 4 + q) * 16 + nn) * 8;
    float4v acc = (float4v){0.f, 0.f, 0.f, 0.f};
    #pragma unroll
    for (int ks = 0; ks < 6; ++ks) {
        short8 ah = *(const short8*)&Atile[ks * 544 + q * 136 + nn * 8];
        short8 bh = *(const short8*)(bt0 + ks * 512);
        short8 bl = *(const short8*)(bt1 + ks * 512);
        acc = __builtin_amdgcn_mfma_f32_16x16x32_bf16(ah, bh, acc, 0, 0, 0);
        acc = __builtin_amdgcn_mfma_f32_16x16x32_bf16(ah, bl, acc, 0, 0, 0);
    }
    // D: col f = wv*16+nn, row = t0 + q*4 + r
    #pragma unroll
    for (int r = 0; r < 4; ++r) {
        int row = t0 + q * 4 + r;
        if (row < n_nodes) {
            if (last_layer)
                out[(size_t)row * 64 + wv * 16 + nn] = acc[r];
            else
                hnext[(size_t)row * 64 + wv * 16 + nn] = f2bf(acc[r]);
        }
    }
}

extern "C" void kernel_launch(void* const* d_in, const int* in_sizes, int n_in,
                              void* d_out, int out_size, void* d_ws, size_t ws_size,
                              hipStream_t stream)
{
    const float* feat   = (const float*)d_in[0];   // [N, 64]
    const float* pseudo = (const float*)d_in[1];   // [E, 2]
    const int*   rowptr = (const int*)d_in[2];     // [N+1]
    const int*   colind = (const int*)d_in[3];     // [E]
    const float* projW  = (const float*)d_in[4];   // [L, 2, 2]
    const float* projB  = (const float*)d_in[5];   // [L, 2]
    const float* fcW    = (const float*)d_in[6];   // [L, 64, 192]
    const float* mu     = (const float*)d_in[7];   // [L, 3, 2]
    const float* isg    = (const float*)d_in[8];   // [L, 3, 2]
    float* out = (float*)d_out;

    int n  = in_sizes[0] / FEAT;                        // 50000
    int n_layers = in_sizes[6] / (FEAT * NKERN * FEAT); // 3

    unsigned short* hbA = (unsigned short*)d_ws;                  // n*64
    unsigned short* hbB = hbA + (size_t)n * FEAT;                 // n*64
    unsigned short* Bth = hbB + (size_t)n * FEAT;                 // L*12288
    unsigned short* Btl = Bth + (size_t)n_layers * 12288;         // L*12288

    int n4 = n * FEAT / 4;
    int totalW = n_layers * FEAT * 192;
    int castBlocks = (n4 + 255) / 256;
    int wpBlocks   = (totalW + 255) / 256;

    dim3 blk(256);
    dim3 prepGrid(castBlocks + wpBlocks);
    dim3 layerGrid((n + 15) / 16);
    dim3 layerBlk(256);

    prep_kernel<<<prepGrid, blk, 0, stream>>>(
        feat, hbA, n4, fcW, Bth, Btl, totalW, castBlocks);

    const unsigned short* hin = hbA;
    for (int l = 0; l < n_layers; ++l) {
        int last = (l == n_layers - 1);
        unsigned short* hb_out = (l == 0) ? hbB : hbA;
        layer_kernel<<<layerGrid, layerBlk, 0, stream>>>(
            hin, rowptr, colind, pseudo, projW, projB, mu, isg, l,
            Bth + (size_t)l * 12288, Btl + (size_t)l * 12288,
            out, hb_out, n, last);
        hin = hb_out;
    }
}

// Round 4
// 166.423 us; speedup vs baseline: 1.4727x; 1.0081x over previous
//
#include <hip/hip_runtime.h>
#include <math.h>

#define FEAT 64
#define NKERN 3

typedef __attribute__((ext_vector_type(8))) short short8;
typedef __attribute__((ext_vector_type(4))) float float4v;
typedef __attribute__((ext_vector_type(2))) float float2v;

__device__ __forceinline__ unsigned short f2bf(float f) {
    unsigned int u = __float_as_uint(f);
    u = (u + 0x7fffu + ((u >> 16) & 1u)) >> 16;   // round-to-nearest-even
    return (unsigned short)u;
}
__device__ __forceinline__ float bf2f(unsigned short b) {
    return __uint_as_float(((unsigned int)b) << 16);
}
// fast tanh: 1 - 2/(e^{2x}+1), exact at +-inf, bf16-level accurate
__device__ __forceinline__ float fast_tanh(float x) {
    float e = __expf(2.f * x);
    return fmaf(-2.f, __builtin_amdgcn_rcpf(e + 1.f), 1.f);
}

// Combined prep: feat fp32->bf16 cast (first nCastBlocks) + fcW frag-tiling.
__global__ __launch_bounds__(256) void prep_kernel(
    const float* __restrict__ x, unsigned short* __restrict__ y, int n4,
    const float* __restrict__ fcW,
    unsigned short* __restrict__ Bth, unsigned short* __restrict__ Btl,
    int totalW, int nCastBlocks)
{
    int b = blockIdx.x;
    if (b < nCastBlocks) {
        int i = b * 256 + threadIdx.x;
        if (i >= n4) return;
        float4 v = ((const float4*)x)[i];
        ushort4 o;
        o.x = f2bf(v.x); o.y = f2bf(v.y); o.z = f2bf(v.z); o.w = f2bf(v.w);
        ((ushort4*)y)[i] = o;
    } else {
        int idx = (b - nCastBlocks) * 256 + threadIdx.x;
        if (idx >= totalW) return;
        int l   = idx / (FEAT * 192);
        int rem = idx - l * (FEAT * 192);
        int f   = rem / 192;
        int jp  = rem - f * 192;
        int k = jp >> 6, j = jp & 63;
        float v = fcW[(size_t)l * 12288 + j * 192 + k * 64 + f];
        unsigned short hi = f2bf(v);
        int dst = l * 12288 +
                  ((((f >> 4) * 6 + (jp >> 5)) * 4 + ((jp >> 3) & 3)) * 16 + (f & 15)) * 8 +
                  (jp & 7);
        Bth[dst] = hi;
        Btl[dst] = f2bf(v - bf2f(hi));
    }
}

// One fused layer: block = 4 waves = 256 threads, tile = 16 nodes.
// Phase 1 (restructured for memory-level parallelism):
//   Step A (both node-pairs upfront): lane = (node=half, edge=p); per-edge
//     Gaussian weights; 16B LDS record [cc<<7, w0, w1, w2] for all 4 nodes.
//   Step B: ONE combined loop over 32 edges, BOTH pairs interleaved =
//     2 independent ds_read->gather->FMA chains; #pragma unroll 4 => 8 LDS
//     reads + 8 gathers schedulable per body. Fix targets dep-chain latency
//     x insufficient outstanding loads (prior rounds' VALU cuts were neutral).
// Phase 2: ALL 4 waves do MFMA (wave = f-tile), unchanged (verified).
// __launch_bounds__(256,6): VGPR cap ~85 -> 6 waves/SIMD residency.
__global__ __launch_bounds__(256, 6) void layer_kernel(
    const unsigned short* __restrict__ h,    // [N, 64] bf16
    const int*   __restrict__ rowptr,        // [N+1]
    const int*   __restrict__ colind,        // [E]
    const float* __restrict__ pseudo,        // [E, 2]
    const float* __restrict__ projW,         // [L, 2, 2]
    const float* __restrict__ projB,         // [L, 2]
    const float* __restrict__ mu,            // [L, 3, 2]
    const float* __restrict__ isg,           // [L, 3, 2]
    int layer,
    const unsigned short* __restrict__ Bth,  // frag-tiled, this layer
    const unsigned short* __restrict__ Btl,
    float* __restrict__ out,                 // [N,64] fp32 (last layer)
    unsigned short* __restrict__ hnext,      // [N,64] bf16 (mid layers)
    int n_nodes, int last_layer)
{
    __shared__ __align__(16) unsigned short Atile[3264];     // 6 ks * 544 shorts
    __shared__ __align__(16) unsigned int   Wlds[4][4][128]; // 4 waves x 4 node-slots
    int tid  = threadIdx.x;
    int wv   = tid >> 6;
    int lane = tid & 63;
    int t0   = blockIdx.x * 16;

    // per-layer constants (uniform s_loads, once)
    const float* pw = projW + layer * 4;
    const float* pb = projB + layer * 2;
    const float* mm = mu  + layer * 6;
    const float* ss = isg + layer * 6;
    float pw0 = pw[0], pw1 = pw[1], pw2 = pw[2], pw3 = pw[3];
    float pb0 = pb[0], pb1 = pb[1];
    float m0 = mm[0], m1 = mm[1], m2 = mm[2], m3 = mm[3], m4 = mm[4], m5 = mm[5];
    float c0 = -0.5f * ss[0] * ss[0], c1 = -0.5f * ss[1] * ss[1];
    float c2 = -0.5f * ss[2] * ss[2], c3 = -0.5f * ss[3] * ss[3];
    float c4 = -0.5f * ss[4] * ss[4], c5 = -0.5f * ss[5] * ss[5];

    int half = lane >> 5;
    int p    = lane & 31;
    unsigned int featoff = (unsigned int)(p * 4);   // byte off of feat pair in bf16 row
    const char* hb = (const char*)h;

    // ---- Step A: per-edge records for ALL 4 nodes of this wave ----
    bool fastp[2];
    #pragma unroll
    for (int t = 0; t < 2; ++t) {
        int node = t0 + wv * 4 + t * 2 + half;
        int ncl  = node < n_nodes - 1 ? node : (n_nodes - 1);
        int rp   = rowptr[ncl];
        int deg  = rowptr[ncl + 1] - rp;
        bool fast = __all((deg == 32) && (node < n_nodes));
        fastp[t] = fast;
        if (fast) {
            int ei = rp + p;
            int cc = colind[ei];                       // coalesced dword
            float2 ps = ((const float2*)pseudo)[ei];   // coalesced 8B
            float u0 = fast_tanh(fmaf(ps.x, pw0, fmaf(ps.y, pw2, pb0)));
            float u1 = fast_tanh(fmaf(ps.x, pw1, fmaf(ps.y, pw3, pb1)));
            float d0 = u0 - m0, d1 = u1 - m1;
            float w0v = __expf(fmaf(d0 * d0, c0, d1 * d1 * c1));
            d0 = u0 - m2; d1 = u1 - m3;
            float w1v = __expf(fmaf(d0 * d0, c2, d1 * d1 * c3));
            d0 = u0 - m4; d1 = u1 - m5;
            float w2v = __expf(fmaf(d0 * d0, c4, d1 * d1 * c5));
            uint4 recw;
            recw.x = ((unsigned int)cc) << 7;          // byte offset of row
            recw.y = __float_as_uint(w0v);
            recw.z = __float_as_uint(w1v);
            recw.w = __float_as_uint(w2v);
            *(uint4*)&Wlds[wv][t * 2 + half][p * 4] = recw;  // ds_write_b128
        }
    }

    if (fastp[0] && fastp[1]) {
        // ---- Step B: combined loop, 2 independent chains (pair0, pair1) ----
        const unsigned int* WA = &Wlds[wv][half][0];       // pair0, slot half
        const unsigned int* WB = &Wlds[wv][2 + half][0];   // pair1, slot 2+half
        float2v aA0 = {0.f, 0.f}, aA1 = {0.f, 0.f}, aA2 = {0.f, 0.f};
        float2v aB0 = {0.f, 0.f}, aB1 = {0.f, 0.f}, aB2 = {0.f, 0.f};
        #pragma unroll 4
        for (int i = 0; i < 32; ++i) {
            uint4 rA = *(const uint4*)(WA + i * 4);    // ds_read_b128 broadcast
            uint4 rB = *(const uint4*)(WB + i * 4);
            unsigned int hA = *(const unsigned int*)(hb + (rA.x + featoff));
            unsigned int hB = *(const unsigned int*)(hb + (rB.x + featoff));
            float2v vA, vB;
            vA.x = __uint_as_float(hA << 16);
            vA.y = __uint_as_float(hA & 0xffff0000u);
            vB.x = __uint_as_float(hB << 16);
            vB.y = __uint_as_float(hB & 0xffff0000u);
            float wA0 = __uint_as_float(rA.y), wA1 = __uint_as_float(rA.z), wA2 = __uint_as_float(rA.w);
            float wB0 = __uint_as_float(rB.y), wB1 = __uint_as_float(rB.z), wB2 = __uint_as_float(rB.w);
#if __has_builtin(__builtin_elementwise_fma)
            float2v sA0 = {wA0, wA0}, sA1 = {wA1, wA1}, sA2 = {wA2, wA2};
            float2v sB0 = {wB0, wB0}, sB1 = {wB1, wB1}, sB2 = {wB2, wB2};
            aA0 = __builtin_elementwise_fma(vA, sA0, aA0);
            aA1 = __builtin_elementwise_fma(vA, sA1, aA1);
            aA2 = __builtin_elementwise_fma(vA, sA2, aA2);
            aB0 = __builtin_elementwise_fma(vB, sB0, aB0);
            aB1 = __builtin_elementwise_fma(vB, sB1, aB1);
            aB2 = __builtin_elementwise_fma(vB, sB2, aB2);
#else
            aA0.x = fmaf(vA.x, wA0, aA0.x); aA0.y = fmaf(vA.y, wA0, aA0.y);
            aA1.x = fmaf(vA.x, wA1, aA1.x); aA1.y = fmaf(vA.y, wA1, aA1.y);
            aA2.x = fmaf(vA.x, wA2, aA2.x); aA2.y = fmaf(vA.y, wA2, aA2.y);
            aB0.x = fmaf(vB.x, wB0, aB0.x); aB0.y = fmaf(vB.y, wB0, aB0.y);
            aB1.x = fmaf(vB.x, wB1, aB1.x); aB1.y = fmaf(vB.y, wB1, aB1.y);
            aB2.x = fmaf(vB.x, wB2, aB2.x); aB2.y = fmaf(vB.y, wB2, aB2.y);
#endif
        }
        // ---- epilogue: pack 2 feats -> dword, A-frag layout (verified) ----
        int j0 = p * 2;
        int sa = (j0 >> 5) * 544 + ((j0 >> 3) & 3) * 136 + (j0 & 7);
        int sa0 = sa + (wv * 4 + half) * 8;        // pair0 row m
        int sa1 = sa + (wv * 4 + 2 + half) * 8;    // pair1 row m
        unsigned int k0, k1, k2, k3, k4, k5;
        asm("v_cvt_pk_bf16_f32 %0, %1, %2" : "=v"(k0) : "v"(aA0.x), "v"(aA0.y));
        asm("v_cvt_pk_bf16_f32 %0, %1, %2" : "=v"(k1) : "v"(aA1.x), "v"(aA1.y));
        asm("v_cvt_pk_bf16_f32 %0, %1, %2" : "=v"(k2) : "v"(aA2.x), "v"(aA2.y));
        asm("v_cvt_pk_bf16_f32 %0, %1, %2" : "=v"(k3) : "v"(aB0.x), "v"(aB0.y));
        asm("v_cvt_pk_bf16_f32 %0, %1, %2" : "=v"(k4) : "v"(aB1.x), "v"(aB1.y));
        asm("v_cvt_pk_bf16_f32 %0, %1, %2" : "=v"(k5) : "v"(aB2.x), "v"(aB2.y));
        *(unsigned int*)&Atile[sa0]        = k0;
        *(unsigned int*)&Atile[sa0 + 1088] = k1;
        *(unsigned int*)&Atile[sa0 + 2176] = k2;
        *(unsigned int*)&Atile[sa1]        = k3;
        *(unsigned int*)&Atile[sa1 + 1088] = k4;
        *(unsigned int*)&Atile[sa1 + 2176] = k5;
    } else {
        // generic serial path (tail / irregular degree; never hot here)
        for (int mq = 0; mq < 4; ++mq) {
            int node = t0 + wv * 4 + mq;
            float a0 = 0.f, a1 = 0.f, a2 = 0.f;
            if (node < n_nodes) {
                int nu = __builtin_amdgcn_readfirstlane(node);
                int r0 = rowptr[nu];
                int dg = rowptr[nu + 1] - r0;
                for (int i = 0; i < dg; ++i) {
                    int cc = colind[r0 + i];
                    float px = pseudo[(size_t)(r0 + i) * 2];
                    float py = pseudo[(size_t)(r0 + i) * 2 + 1];
                    float u0 = fast_tanh(fmaf(px, pw0, fmaf(py, pw2, pb0)));
                    float u1 = fast_tanh(fmaf(px, pw1, fmaf(py, pw3, pb1)));
                    float d0 = u0 - m0, d1 = u1 - m1;
                    float w0e = __expf(fmaf(d0 * d0, c0, d1 * d1 * c1));
                    d0 = u0 - m2; d1 = u1 - m3;
                    float w1e = __expf(fmaf(d0 * d0, c2, d1 * d1 * c3));
                    d0 = u0 - m4; d1 = u1 - m5;
                    float w2e = __expf(fmaf(d0 * d0, c4, d1 * d1 * c5));
                    float vf = bf2f(h[(size_t)cc * FEAT + lane]);
                    a0 = fmaf(w0e, vf, a0);
                    a1 = fmaf(w1e, vf, a1);
                    a2 = fmaf(w2e, vf, a2);
                }
            }
            int sb = (lane >> 5) * 544 + ((lane >> 3) & 3) * 136 + (wv * 4 + mq) * 8 + (lane & 7);
            Atile[sb]        = f2bf(a0);
            Atile[sb + 1088] = f2bf(a1);
            Atile[sb + 2176] = f2bf(a2);
        }
    }
    __syncthreads();

    // Phase 2: wave wv = f-tile; B hi/lo frags from pre-tiled, L2-resident Bt.
    int q  = lane >> 4;
    int nn = lane & 15;
    const unsigned short* bt0 = Bth + (((wv * 6) * 4 + q) * 16 + nn) * 8;
    const unsigned short* bt1 = Btl + (((wv * 6) * 4 + q) * 16 + nn) * 8;
    float4v acc = (float4v){0.f, 0.f, 0.f, 0.f};
    #pragma unroll
    for (int ks = 0; ks < 6; ++ks) {
        short8 ah = *(const short8*)&Atile[ks * 544 + q * 136 + nn * 8];
        short8 bh = *(const short8*)(bt0 + ks * 512);
        short8 bl = *(const short8*)(bt1 + ks * 512);
        acc = __builtin_amdgcn_mfma_f32_16x16x32_bf16(ah, bh, acc, 0, 0, 0);
        acc = __builtin_amdgcn_mfma_f32_16x16x32_bf16(ah, bl, acc, 0, 0, 0);
    }
    // D: col f = wv*16+nn, row = t0 + q*4 + r
    #pragma unroll
    for (int r = 0; r < 4; ++r) {
        int row = t0 + q * 4 + r;
        if (row < n_nodes) {
            if (last_layer)
                out[(size_t)row * 64 + wv * 16 + nn] = acc[r];
            else
                hnext[(size_t)row * 64 + wv * 16 + nn] = f2bf(acc[r]);
        }
    }
}

extern "C" void kernel_launch(void* const* d_in, const int* in_sizes, int n_in,
                              void* d_out, int out_size, void* d_ws, size_t ws_size,
                              hipStream_t stream)
{
    const float* feat   = (const float*)d_in[0];   // [N, 64]
    const float* pseudo = (const float*)d_in[1];   // [E, 2]
    const int*   rowptr = (const int*)d_in[2];     // [N+1]
    const int*   colind = (const int*)d_in[3];     // [E]
    const float* projW  = (const float*)d_in[4];   // [L, 2, 2]
    const float* projB  = (const float*)d_in[5];   // [L, 2]
    const float* fcW    = (const float*)d_in[6];   // [L, 64, 192]
    const float* mu     = (const float*)d_in[7];   // [L, 3, 2]
    const float* isg    = (const float*)d_in[8];   // [L, 3, 2]
    float* out = (float*)d_out;

    int n  = in_sizes[0] / FEAT;                        // 50000
    int n_layers = in_sizes[6] / (FEAT * NKERN * FEAT); // 3

    unsigned short* hbA = (unsigned short*)d_ws;                  // n*64
    unsigned short* hbB = hbA + (size_t)n * FEAT;                 // n*64
    unsigned short* Bth = hbB + (size_t)n * FEAT;                 // L*12288
    unsigned short* Btl = Bth + (size_t)n_layers * 12288;         // L*12288

    int n4 = n * FEAT / 4;
    int totalW = n_layers * FEAT * 192;
    int castBlocks = (n4 + 255) / 256;
    int wpBlocks   = (totalW + 255) / 256;

    dim3 blk(256);
    dim3 prepGrid(castBlocks + wpBlocks);
    dim3 layerGrid((n + 15) / 16);
    dim3 layerBlk(256);

    prep_kernel<<<prepGrid, blk, 0, stream>>>(
        feat, hbA, n4, fcW, Bth, Btl, totalW, castBlocks);

    const unsigned short* hin = hbA;
    for (int l = 0; l < n_layers; ++l) {
        int last = (l == n_layers - 1);
        unsigned short* hb_out = (l == 0) ? hbB : hbA;
        layer_kernel<<<layerGrid, layerBlk, 0, stream>>>(
            hin, rowptr, colind, pseudo, projW, projB, mu, isg, l,
            Bth + (size_t)l * 12288, Btl + (size_t)l * 12288,
            out, hb_out, n, last);
        hin = hb_out;
    }
}